// Round 8
// baseline (2542.506 us; speedup 1.0000x reference)
//
#include <hip/hip_runtime.h>
#include <hip/hip_bf16.h>

// Matryoshka linear: y[m][n] = sum_k x[m][k] * W_seg[n_local][k]
//   seg0: n in [0,1024),    K=1024   seg1: n in [1024,2048), K=2048
//   seg2: n in [2048,4096), K=4096   M = 16384, out [16384][4096] f32
//
// Round 8: r3 structure at 2 blocks/CU. Single lever vs round 3:
//   4-buffer (128 KB) -> 2-buffer (64 KB) LDS, prefetch distance 1,
//   end-of-tile vmcnt(0); __launch_bounds__(512,4).
// Mechanism (m114): with 2 co-resident blocks, one block's LDS-read burst
// and barrier drain overlap the other block's MFMA backlog — inter-block
// pipe overlap instead of the failed intra-block phase scheduling
// (r4/r5/r7 all regressed vs r3's serial 2714 cy/tile).
// Swizzle, grid mapping, staging formulas, epilogue: identical to round 3
// (verified 0 bank conflicts, absmax 0.0156).

typedef short bf16x8 __attribute__((ext_vector_type(8)));
typedef float f32x4 __attribute__((ext_vector_type(4)));

__device__ __forceinline__ ushort f2bf(float f) {
  union { float f; unsigned u; } c; c.f = f;
  unsigned u = c.u;
  unsigned r = u + 0x7fffu + ((u >> 16) & 1u);  // RNE
  return (ushort)(r >> 16);
}

// One fused convert: dst (bf16) is contiguous in ws = [x | W0 | W1 | W2].
__global__ void cvt_all_bf16(const float* __restrict__ x,
                             const float* __restrict__ W0,
                             const float* __restrict__ W1,
                             const float* __restrict__ W2,
                             ushort* __restrict__ dst) {
  const int X4  = 16777216;             // xN/4
  const int E0  = X4 + 262144;          // + w0N/4
  const int E1  = E0 + 524288;          // + w1N/4
  const int E2  = E1 + 2097152;         // + w2N/4 (total float4 count)
  int i = blockIdx.x * blockDim.x + threadIdx.x;
  int stride = gridDim.x * blockDim.x;
  ushort4* out4 = (ushort4*)dst;
  for (int j = i; j < E2; j += stride) {
    const float4* src;
    if (j < X4)      src = (const float4*)x  + j;
    else if (j < E0) src = (const float4*)W0 + (j - X4);
    else if (j < E1) src = (const float4*)W1 + (j - E0);
    else             src = (const float4*)W2 + (j - E1);
    float4 v = *src;
    ushort4 o;
    o.x = f2bf(v.x); o.y = f2bf(v.y); o.z = f2bf(v.z); o.w = f2bf(v.w);
    out4[j] = o;
  }
}

__device__ __forceinline__ void gload16(const ushort* g, const ushort* l) {
  __builtin_amdgcn_global_load_lds(
      (const __attribute__((address_space(1))) void*)g,
      (__attribute__((address_space(3))) void*)l, 16, 0, 0);
}

#define TILE_E 8192   // one 256x32 bf16 tile = 16 KB = 8192 ushorts

#define MF(av, bv, mi, ni) \
  acc[mi][ni] = __builtin_amdgcn_mfma_f32_16x16x32_bf16(av, bv, acc[mi][ni], 0, 0, 0)

__global__ __launch_bounds__(512, 4) void matry_gemm(
    const ushort* __restrict__ xbf,   // [16384][4096] bf16
    const ushort* __restrict__ w0,    // [1024][1024]
    const ushort* __restrict__ w1,    // [1024][2048]
    const ushort* __restrict__ w2,    // [2048][4096]
    float* __restrict__ out) {        // [16384][4096] f32
  __shared__ __align__(16) ushort sA[2][TILE_E];   // 2-buffer: 64 KB total
  __shared__ __align__(16) ushort sB[2][TILE_E];

  const int bid = blockIdx.x;
  const int rt = bid & 63;    // row tile fastest: same-rt blocks (A reuse)
  const int ct = bid >> 6;    // land on the same XCD (64 % 8 == 0)

  int K; const ushort* W; int nl0;
  if (ct < 4)      { K = 1024; W = w0; nl0 = ct * 256; }
  else if (ct < 8) { K = 2048; W = w1; nl0 = (ct - 4) * 256; }
  else             { K = 4096; W = w2; nl0 = (ct - 8) * 256; }
  const int NT = K >> 5;          // K-tiles of 32
  const int m0 = rt * 256;
  const int n0 = ct * 256;

  const int tid  = threadIdx.x;
  const int wid  = tid >> 6;
  const int lane = tid & 63;
  const int wm = wid >> 2;        // 0..1  (row half)
  const int wn = wid & 3;         // 0..3  (col quarter)
  const int fr = lane & 15;
  // conflict-free slot (round 3, verified 0 conflicts):
  // quad = 4*(fr&1) + (h ^ ((fr>>1)&3)) covers all 8 bank-quads per 8 lanes
  const int swz_e = (((lane >> 4) ^ ((lane >> 1) & 3)) << 3);

  // ---- staging (pre-swizzled global source, linear LDS dest) ----
  // LDS slot s of row r holds k-chunk  s ^ ((r>>1)&3).
  const int srow = tid >> 2;                                   // 0..127
  const int scol = (((tid & 3) ^ ((tid >> 3) & 3)) << 3);      // elements
  const ushort* Asrc0 = xbf + (size_t)(m0 + srow) * 4096 + scol;
  const ushort* Asrc1 = Asrc0 + (size_t)128 * 4096;
  const ushort* Bsrc0 = W + (size_t)(nl0 + srow) * K + scol;
  const ushort* Bsrc1 = Bsrc0 + (size_t)128 * K;
  const int d0 = tid * 8;          // LDS element offset, issue 0
  const int d1 = 4096 + tid * 8;   // issue 1 (rows 128..255)

  f32x4 acc[8][4];
#pragma unroll
  for (int mi = 0; mi < 8; ++mi)
#pragma unroll
    for (int ni = 0; ni < 4; ++ni)
      acc[mi][ni] = (f32x4){0.f, 0.f, 0.f, 0.f};

  // ---- prologue: stage tile 0 into buf 0 ----
  gload16(Asrc0, &sA[0][d0]);
  gload16(Asrc1, &sA[0][d1]);
  gload16(Bsrc0, &sB[0][d0]);
  gload16(Bsrc1, &sB[0][d1]);
  asm volatile("s_waitcnt vmcnt(0)" ::: "memory");
  __builtin_amdgcn_s_barrier();

  // ---- main loop: 1 K-tile per iteration, r3 single-barrier shape ----
  for (int t = 0; t < NT; ++t) {
    const int b = t & 1, nb = b ^ 1;
    const ushort* pa = &sA[b][(wm * 128 + fr) * 32 + swz_e];
    const ushort* pb = &sB[b][(wn * 64 + fr) * 32 + swz_e];
    // stage tile t+1 (clamped on last iter: redundant write to a buffer
    // that is never read again — keeps the loop branch-free)
    const int ts = (t + 1 < NT) ? (t + 1) : (NT - 1);
    const int ks = ts << 5;

    // ---- half 1: reads for mi 0..3 (+ all B) || stage A-half ----
    bf16x8 a0 = *(const bf16x8*)(pa);
    bf16x8 a1 = *(const bf16x8*)(pa + 512);
    bf16x8 a2 = *(const bf16x8*)(pa + 1024);
    bf16x8 a3 = *(const bf16x8*)(pa + 1536);
    bf16x8 b0 = *(const bf16x8*)(pb);
    bf16x8 b1 = *(const bf16x8*)(pb + 512);
    bf16x8 b2 = *(const bf16x8*)(pb + 1024);
    bf16x8 b3 = *(const bf16x8*)(pb + 1536);
    gload16(Asrc0 + ks, &sA[nb][d0]);
    gload16(Asrc1 + ks, &sA[nb][d1]);
    __builtin_amdgcn_s_setprio(1);
    MF(a0, b0, 0, 0); MF(a0, b1, 0, 1); MF(a0, b2, 0, 2); MF(a0, b3, 0, 3);
    MF(a1, b0, 1, 0); MF(a1, b1, 1, 1); MF(a1, b2, 1, 2); MF(a1, b3, 1, 3);
    MF(a2, b0, 2, 0); MF(a2, b1, 2, 1); MF(a2, b2, 2, 2); MF(a2, b3, 2, 3);
    MF(a3, b0, 3, 0); MF(a3, b1, 3, 1); MF(a3, b2, 3, 2); MF(a3, b3, 3, 3);
    __builtin_amdgcn_s_setprio(0);

    // ---- half 2: reads for mi 4..7 || stage B-half ----
    bf16x8 a4 = *(const bf16x8*)(pa + 2048);
    bf16x8 a5 = *(const bf16x8*)(pa + 2560);
    bf16x8 a6 = *(const bf16x8*)(pa + 3072);
    bf16x8 a7 = *(const bf16x8*)(pa + 3584);
    gload16(Bsrc0 + ks, &sB[nb][d0]);
    gload16(Bsrc1 + ks, &sB[nb][d1]);
    __builtin_amdgcn_s_setprio(1);
    MF(a4, b0, 4, 0); MF(a4, b1, 4, 1); MF(a4, b2, 4, 2); MF(a4, b3, 4, 3);
    MF(a5, b0, 5, 0); MF(a5, b1, 5, 1); MF(a5, b2, 5, 2); MF(a5, b3, 5, 3);
    MF(a6, b0, 6, 0); MF(a6, b1, 6, 1); MF(a6, b2, 6, 2); MF(a6, b3, 6, 3);
    MF(a7, b0, 7, 0); MF(a7, b1, 7, 1); MF(a7, b2, 7, 2); MF(a7, b3, 7, 3);
    __builtin_amdgcn_s_setprio(0);

    // 2-buffer: all 4 loads for tile t+1 must land before next iteration
    asm volatile("s_waitcnt vmcnt(0)" ::: "memory");
    __builtin_amdgcn_s_barrier();
  }

  // ---- epilogue: C/D layout col=lane&15, row=(lane>>4)*4+reg [m89] ----
  const int rq = (lane >> 4) * 4;
#pragma unroll
  for (int mi = 0; mi < 8; ++mi) {
#pragma unroll
    for (int ni = 0; ni < 4; ++ni) {
      const int n = n0 + wn * 64 + ni * 16 + fr;
#pragma unroll
      for (int r = 0; r < 4; ++r) {
        const int m = m0 + wm * 128 + mi * 16 + rq + r;
        out[(size_t)m * 4096 + n] = acc[mi][ni][r];
      }
    }
  }
}

// Correct-but-slow fallback if workspace is too small.
__global__ void naive_kernel(const float* __restrict__ x,
                             const float* __restrict__ W0,
                             const float* __restrict__ W1,
                             const float* __restrict__ W2,
                             float* __restrict__ out) {
  long idx = (long)blockIdx.x * 256 + threadIdx.x;
  int n = (int)(idx & 4095);
  long m = idx >> 12;
  int K; const float* W; int nl;
  if (n < 1024)      { K = 1024; W = W0; nl = n; }
  else if (n < 2048) { K = 2048; W = W1; nl = n - 1024; }
  else               { K = 4096; W = W2; nl = n - 2048; }
  const float* xr = x + m * 4096;
  const float* wr = W + (long)nl * K;
  float s = 0.f;
  for (int k = 0; k < K; ++k) s += xr[k] * wr[k];
  out[idx] = s;
}

extern "C" void kernel_launch(void* const* d_in, const int* in_sizes, int n_in,
                              void* d_out, int out_size, void* d_ws,
                              size_t ws_size, hipStream_t stream) {
  const float* x  = (const float*)d_in[0];
  const float* W0 = (const float*)d_in[1];
  const float* W1 = (const float*)d_in[2];
  const float* W2 = (const float*)d_in[3];
  float* out = (float*)d_out;

  const size_t xN  = (size_t)16384 * 4096;
  const size_t w0N = (size_t)1024 * 1024;
  const size_t w1N = (size_t)1024 * 2048;
  const size_t w2N = (size_t)2048 * 4096;
  const size_t need = (xN + w0N + w1N + w2N) * sizeof(ushort);  // ~150 MB

  if (ws_size >= need) {
    ushort* xbf = (ushort*)d_ws;
    ushort* w0b = xbf + xN;
    ushort* w1b = w0b + w0N;
    ushort* w2b = w1b + w1N;
    cvt_all_bf16<<<4096, 256, 0, stream>>>(x, W0, W1, W2, xbf);
    // grid: 64 row-tiles (fast) x 16 col-tiles (slow)
    matry_gemm<<<1024, 512, 0, stream>>>(xbf, w0b, w1b, w2b, out);
  } else {
    naive_kernel<<<(int)((xN + 255) / 256), 256, 0, stream>>>(x, W0, W1, W2, out);
  }
}

// Round 9
// 546.770 us; speedup vs baseline: 4.6500x; 4.6500x over previous
//
#include <hip/hip_runtime.h>
#include <hip/hip_bf16.h>

// Matryoshka linear: y[m][n] = sum_k x[m][k] * W_seg[n_local][k]
//   seg0: n in [0,1024),    K=1024   seg1: n in [1024,2048), K=2048
//   seg2: n in [2048,4096), K=4096   M = 16384, out [16384][4096] f32
//
// Round 9: r3 structure (best: 398us GEMM) with 32x32x16 MFMA instead of
// 16x16x32. Same FLOPs in 128 instrs/tile instead of 256; matrix-pipe time
// 1242 -> 1033 cy/tile (ubench 2382 vs 2075 TF). LDS bytes unchanged
// (12 x ds_read_b128 per wave per tile). Staging, swizzle, 4-buffer
// prefetch-3 rotation, vmcnt(8), single barrier per tile: identical to r3.
// Fragment layouts (guide s3, m74/m101):
//   A/B: lane l holds [row=l&31][k=(l>>5)*8+j]  (k-chunk = 2*ks + (l>>5))
//   C/D: col=lane&31, row=(reg&3)+8*(reg>>2)+4*(lane>>5), reg 0..15

typedef short bf16x8 __attribute__((ext_vector_type(8)));
typedef float f32x16 __attribute__((ext_vector_type(16)));

__device__ __forceinline__ ushort f2bf(float f) {
  union { float f; unsigned u; } c; c.f = f;
  unsigned u = c.u;
  unsigned r = u + 0x7fffu + ((u >> 16) & 1u);  // RNE
  return (ushort)(r >> 16);
}

// One fused convert: dst (bf16) is contiguous in ws = [x | W0 | W1 | W2].
__global__ void cvt_all_bf16(const float* __restrict__ x,
                             const float* __restrict__ W0,
                             const float* __restrict__ W1,
                             const float* __restrict__ W2,
                             ushort* __restrict__ dst) {
  const int X4  = 16777216;             // xN/4
  const int E0  = X4 + 262144;          // + w0N/4
  const int E1  = E0 + 524288;          // + w1N/4
  const int E2  = E1 + 2097152;         // + w2N/4 (total float4 count)
  int i = blockIdx.x * blockDim.x + threadIdx.x;
  int stride = gridDim.x * blockDim.x;
  ushort4* out4 = (ushort4*)dst;
  for (int j = i; j < E2; j += stride) {
    const float4* src;
    if (j < X4)      src = (const float4*)x  + j;
    else if (j < E0) src = (const float4*)W0 + (j - X4);
    else if (j < E1) src = (const float4*)W1 + (j - E0);
    else             src = (const float4*)W2 + (j - E1);
    float4 v = *src;
    ushort4 o;
    o.x = f2bf(v.x); o.y = f2bf(v.y); o.z = f2bf(v.z); o.w = f2bf(v.w);
    out4[j] = o;
  }
}

__device__ __forceinline__ void gload16(const ushort* g, const ushort* l) {
  __builtin_amdgcn_global_load_lds(
      (const __attribute__((address_space(1))) void*)g,
      (__attribute__((address_space(3))) void*)l, 16, 0, 0);
}

#define TILE_E 8192   // one 256x32 bf16 tile = 16 KB = 8192 ushorts

#define MF32(av, bv, mb, nb) \
  acc[mb][nb] = __builtin_amdgcn_mfma_f32_32x32x16_bf16(av, bv, acc[mb][nb], 0, 0, 0)

__global__ __launch_bounds__(512, 2) void matry_gemm(
    const ushort* __restrict__ xbf,   // [16384][4096] bf16
    const ushort* __restrict__ w0,    // [1024][1024]
    const ushort* __restrict__ w1,    // [1024][2048]
    const ushort* __restrict__ w2,    // [2048][4096]
    float* __restrict__ out) {        // [16384][4096] f32
  __shared__ __align__(16) ushort sA[4][TILE_E];
  __shared__ __align__(16) ushort sB[4][TILE_E];

  const int bid = blockIdx.x;
  const int rt = bid & 63;    // row tile fastest: same-rt blocks (A reuse)
  const int ct = bid >> 6;    // land on the same XCD (64 % 8 == 0)

  int K; const ushort* W; int nl0;
  if (ct < 4)      { K = 1024; W = w0; nl0 = ct * 256; }
  else if (ct < 8) { K = 2048; W = w1; nl0 = (ct - 4) * 256; }
  else             { K = 4096; W = w2; nl0 = (ct - 8) * 256; }
  const int NT = K >> 5;          // K-tiles of 32
  const int m0 = rt * 256;
  const int n0 = ct * 256;

  const int tid  = threadIdx.x;
  const int wid  = tid >> 6;
  const int lane = tid & 63;
  const int wm = wid >> 2;        // 0..1  (row half)
  const int wn = wid & 3;         // 0..3  (col quarter)
  const int cl = lane & 31;       // fragment row (A) / col (B)
  const int hi = lane >> 5;       // k-chunk half within a k-step
  // swizzle (r3, verified 0 conflicts): LDS slot s of row r holds global
  // k-chunk s ^ ((r>>1)&3). Reader wants chunk 2*ks + hi:
  const int x3 = (lane >> 1) & 3; // = (row>>1)&3 since row≡lane&31 (mod 8)
  const int sw0 = ((hi ^ x3) << 3);        // ks=0 slot offset (elements)
  const int sw1 = (((2 + hi) ^ x3) << 3);  // ks=1 (= sw0 ^ 16)

  // per-lane ds_read bases (elements): A rows wm*128+cl, B rows wn*64+cl
  const int arow = (wm * 128 + cl) * 32;
  const int brow = (wn * 64 + cl) * 32;

  // ---- staging (pre-swizzled global source, linear LDS dest; r3) ----
  const int srow = tid >> 2;                                   // 0..127
  const int scol = (((tid & 3) ^ ((tid >> 3) & 3)) << 3);      // elements
  const ushort* Asrc0 = xbf + (size_t)(m0 + srow) * 4096 + scol;
  const ushort* Asrc1 = Asrc0 + (size_t)128 * 4096;
  const ushort* Bsrc0 = W + (size_t)(nl0 + srow) * K + scol;
  const ushort* Bsrc1 = Bsrc0 + (size_t)128 * K;
  const int d0 = tid * 8;          // LDS element offset, issue 0
  const int d1 = 4096 + tid * 8;   // issue 1 (rows 128..255)

  f32x16 acc[4][2];
#pragma unroll
  for (int mb = 0; mb < 4; ++mb)
#pragma unroll
    for (int nb = 0; nb < 2; ++nb)
#pragma unroll
      for (int r = 0; r < 16; ++r)
        acc[mb][nb][r] = 0.f;

  // ---- prologue: stage tiles 0,1,2 into bufs 0,1,2 ----
#pragma unroll
  for (int pt = 0; pt < 3; ++pt) {
    const int ks = pt * 32;
    gload16(Asrc0 + ks, &sA[pt][d0]);
    gload16(Asrc1 + ks, &sA[pt][d1]);
    gload16(Bsrc0 + ks, &sB[pt][d0]);
    gload16(Bsrc1 + ks, &sB[pt][d1]);
  }
  asm volatile("s_waitcnt vmcnt(8)" ::: "memory");  // tile 0 landed
  __builtin_amdgcn_s_barrier();

  // ---- main loop: 1 K-tile per iteration, r3 single-barrier shape ----
  for (int t = 0; t < NT; ++t) {
    const int b = t & 3;
    const ushort* pa = &sA[b][arow];
    const ushort* pb = &sB[b][brow];
    // stage tile t+3 (clamped in tail: redundant write to a dead buffer)
    const int ts = (t + 3 < NT) ? (t + 3) : (NT - 1);
    const int ks = ts << 5;
    const int bs = (t + 3) & 3;

    // ---- half 1 (ks=0): 4 A + 2 B reads || stage A-half ----
    bf16x8 a0 = *(const bf16x8*)(pa + sw0);
    bf16x8 a1 = *(const bf16x8*)(pa + 1024 + sw0);
    bf16x8 a2 = *(const bf16x8*)(pa + 2048 + sw0);
    bf16x8 a3 = *(const bf16x8*)(pa + 3072 + sw0);
    bf16x8 b0 = *(const bf16x8*)(pb + sw0);
    bf16x8 b1 = *(const bf16x8*)(pb + 1024 + sw0);
    gload16(Asrc0 + ks, &sA[bs][d0]);
    gload16(Asrc1 + ks, &sA[bs][d1]);
    __builtin_amdgcn_s_setprio(1);
    MF32(a0, b0, 0, 0); MF32(a0, b1, 0, 1);
    MF32(a1, b0, 1, 0); MF32(a1, b1, 1, 1);
    MF32(a2, b0, 2, 0); MF32(a2, b1, 2, 1);
    MF32(a3, b0, 3, 0); MF32(a3, b1, 3, 1);
    __builtin_amdgcn_s_setprio(0);

    // ---- half 2 (ks=1): 4 A + 2 B reads || stage B-half ----
    bf16x8 a4 = *(const bf16x8*)(pa + sw1);
    bf16x8 a5 = *(const bf16x8*)(pa + 1024 + sw1);
    bf16x8 a6 = *(const bf16x8*)(pa + 2048 + sw1);
    bf16x8 a7 = *(const bf16x8*)(pa + 3072 + sw1);
    bf16x8 b2 = *(const bf16x8*)(pb + sw1);
    bf16x8 b3 = *(const bf16x8*)(pb + 1024 + sw1);
    gload16(Bsrc0 + ks, &sB[bs][d0]);
    gload16(Bsrc1 + ks, &sB[bs][d1]);
    __builtin_amdgcn_s_setprio(1);
    MF32(a4, b2, 0, 0); MF32(a4, b3, 0, 1);
    MF32(a5, b2, 1, 0); MF32(a5, b3, 1, 1);
    MF32(a6, b2, 2, 0); MF32(a6, b3, 2, 1);
    MF32(a7, b2, 3, 0); MF32(a7, b3, 3, 1);
    __builtin_amdgcn_s_setprio(0);

    // tile t+1's 4 loads (issued at iter t-2) are the oldest of 12 in flight
    asm volatile("s_waitcnt vmcnt(8)" ::: "memory");
    __builtin_amdgcn_s_barrier();
  }

  // ---- epilogue: C/D col=lane&31, row=(reg&3)+8*(reg>>2)+4*hi [m74/m101] ----
  const int hi4 = hi * 4;
#pragma unroll
  for (int mb = 0; mb < 4; ++mb) {
#pragma unroll
    for (int nb = 0; nb < 2; ++nb) {
      const int n = n0 + wn * 64 + nb * 32 + cl;
      const int mbase = m0 + wm * 128 + mb * 32 + hi4;
#pragma unroll
      for (int r = 0; r < 16; ++r) {
        const int m = mbase + (r & 3) + 8 * (r >> 2);
        out[(size_t)m * 4096 + n] = acc[mb][nb][r];
      }
    }
  }
}

// Correct-but-slow fallback if workspace is too small.
__global__ void naive_kernel(const float* __restrict__ x,
                             const float* __restrict__ W0,
                             const float* __restrict__ W1,
                             const float* __restrict__ W2,
                             float* __restrict__ out) {
  long idx = (long)blockIdx.x * 256 + threadIdx.x;
  int n = (int)(idx & 4095);
  long m = idx >> 12;
  int K; const float* W; int nl;
  if (n < 1024)      { K = 1024; W = W0; nl = n; }
  else if (n < 2048) { K = 2048; W = W1; nl = n - 1024; }
  else               { K = 4096; W = W2; nl = n - 2048; }
  const float* xr = x + m * 4096;
  const float* wr = W + (long)nl * K;
  float s = 0.f;
  for (int k = 0; k < K; ++k) s += xr[k] * wr[k];
  out[idx] = s;
}

extern "C" void kernel_launch(void* const* d_in, const int* in_sizes, int n_in,
                              void* d_out, int out_size, void* d_ws,
                              size_t ws_size, hipStream_t stream) {
  const float* x  = (const float*)d_in[0];
  const float* W0 = (const float*)d_in[1];
  const float* W1 = (const float*)d_in[2];
  const float* W2 = (const float*)d_in[3];
  float* out = (float*)d_out;

  const size_t xN  = (size_t)16384 * 4096;
  const size_t w0N = (size_t)1024 * 1024;
  const size_t w1N = (size_t)1024 * 2048;
  const size_t w2N = (size_t)2048 * 4096;
  const size_t need = (xN + w0N + w1N + w2N) * sizeof(ushort);  // ~150 MB

  if (ws_size >= need) {
    ushort* xbf = (ushort*)d_ws;
    ushort* w0b = xbf + xN;
    ushort* w1b = w0b + w0N;
    ushort* w2b = w1b + w1N;
    cvt_all_bf16<<<4096, 256, 0, stream>>>(x, W0, W1, W2, xbf);
    // grid: 64 row-tiles (fast) x 16 col-tiles (slow)
    matry_gemm<<<1024, 512, 0, stream>>>(xbf, w0b, w1b, w2b, out);
  } else {
    naive_kernel<<<(int)((xN + 255) / 256), 256, 0, stream>>>(x, W0, W1, W2, out);
  }
}

// Round 10
// 495.477 us; speedup vs baseline: 5.1314x; 1.1035x over previous
//
#include <hip/hip_runtime.h>
#include <hip/hip_bf16.h>

// Matryoshka linear: y[m][n] = sum_k x[m][k] * W_seg[n_local][k]
//   seg0: n in [0,1024),    K=1024   seg1: n in [1024,2048), K=2048
//   seg2: n in [2048,4096), K=4096   M = 16384, out [16384][4096] f32
//
// Round 10: r3 (best, 398us GEMM) with HALVED sync cadence. Superstep =
// 2 K-tiles: {body(t); vmcnt(4); body(t+1); vmcnt(4); s_barrier}.
// Mid-wait is wave-local (not a barrier) -> wave skew is preserved across
// a whole superstep, doubling the window for cross-wave LDS/MFMA overlap
// (m114). Hazard audit (steady state, 4 gloads/body, stages tile TT+2):
//   entry invariant: outstanding = {T+1:4}
//   body1 stages T+2 -> 8;  vmcnt(4) drains T+1 (read by body2)   OK
//   body2 stages T+3 -> 8;  vmcnt(4) drains T+2 (read next ss)    OK
//   stage targets: buf (TT+2)&3 holds tile TT-2, read 1 superstep ago,
//   all waves past that superstep's closing barrier                OK
// Prologue stages tiles 0,1; vmcnt(4) (tile0 landed); barrier.
// Everything else identical to round 3 (verified: 0 conflicts, absmax
// 0.0156): 256x256 tile, BK=32, XOR swizzle, 4-buffer, setprio, epilogue.

typedef short bf16x8 __attribute__((ext_vector_type(8)));
typedef float f32x4 __attribute__((ext_vector_type(4)));

__device__ __forceinline__ ushort f2bf(float f) {
  union { float f; unsigned u; } c; c.f = f;
  unsigned u = c.u;
  unsigned r = u + 0x7fffu + ((u >> 16) & 1u);  // RNE
  return (ushort)(r >> 16);
}

// One fused convert: dst (bf16) is contiguous in ws = [x | W0 | W1 | W2].
__global__ void cvt_all_bf16(const float* __restrict__ x,
                             const float* __restrict__ W0,
                             const float* __restrict__ W1,
                             const float* __restrict__ W2,
                             ushort* __restrict__ dst) {
  const int X4  = 16777216;             // xN/4
  const int E0  = X4 + 262144;          // + w0N/4
  const int E1  = E0 + 524288;          // + w1N/4
  const int E2  = E1 + 2097152;         // + w2N/4 (total float4 count)
  int i = blockIdx.x * blockDim.x + threadIdx.x;
  int stride = gridDim.x * blockDim.x;
  ushort4* out4 = (ushort4*)dst;
  for (int j = i; j < E2; j += stride) {
    const float4* src;
    if (j < X4)      src = (const float4*)x  + j;
    else if (j < E0) src = (const float4*)W0 + (j - X4);
    else if (j < E1) src = (const float4*)W1 + (j - E0);
    else             src = (const float4*)W2 + (j - E1);
    float4 v = *src;
    ushort4 o;
    o.x = f2bf(v.x); o.y = f2bf(v.y); o.z = f2bf(v.z); o.w = f2bf(v.w);
    out4[j] = o;
  }
}

__device__ __forceinline__ void gload16(const ushort* g, const ushort* l) {
  __builtin_amdgcn_global_load_lds(
      (const __attribute__((address_space(1))) void*)g,
      (__attribute__((address_space(3))) void*)l, 16, 0, 0);
}

#define TILE_E 8192   // one 256x32 bf16 tile = 16 KB = 8192 ushorts

#define MF(av, bv, mi, ni) \
  acc[mi][ni] = __builtin_amdgcn_mfma_f32_16x16x32_bf16(av, bv, acc[mi][ni], 0, 0, 0)

// One K-tile body: 12 ds_read + 4 gload (stage tile TT+2) + 32 MFMA.
#define TILE_BODY(TT)                                                         \
  {                                                                           \
    const int b_ = (TT) & 3;                                                  \
    const ushort* pa = &sA[b_][(wm * 128 + fr) * 32 + swz_e];                 \
    const ushort* pb = &sB[b_][(wn * 64 + fr) * 32 + swz_e];                  \
    const int ts_ = ((TT) + 2 < NT) ? ((TT) + 2) : (NT - 1);                  \
    const int ks_ = ts_ << 5;                                                 \
    const int bs_ = ((TT) + 2) & 3;                                           \
    bf16x8 a0 = *(const bf16x8*)(pa);                                         \
    bf16x8 a1 = *(const bf16x8*)(pa + 512);                                   \
    bf16x8 a2 = *(const bf16x8*)(pa + 1024);                                  \
    bf16x8 a3 = *(const bf16x8*)(pa + 1536);                                  \
    bf16x8 b0 = *(const bf16x8*)(pb);                                         \
    bf16x8 b1 = *(const bf16x8*)(pb + 512);                                   \
    bf16x8 b2 = *(const bf16x8*)(pb + 1024);                                  \
    bf16x8 b3 = *(const bf16x8*)(pb + 1536);                                  \
    gload16(Asrc0 + ks_, &sA[bs_][d0]);                                       \
    gload16(Asrc1 + ks_, &sA[bs_][d1]);                                       \
    __builtin_amdgcn_s_setprio(1);                                            \
    MF(a0, b0, 0, 0); MF(a0, b1, 0, 1); MF(a0, b2, 0, 2); MF(a0, b3, 0, 3);   \
    MF(a1, b0, 1, 0); MF(a1, b1, 1, 1); MF(a1, b2, 1, 2); MF(a1, b3, 1, 3);   \
    MF(a2, b0, 2, 0); MF(a2, b1, 2, 1); MF(a2, b2, 2, 2); MF(a2, b3, 2, 3);   \
    MF(a3, b0, 3, 0); MF(a3, b1, 3, 1); MF(a3, b2, 3, 2); MF(a3, b3, 3, 3);   \
    __builtin_amdgcn_s_setprio(0);                                            \
    bf16x8 a4 = *(const bf16x8*)(pa + 2048);                                  \
    bf16x8 a5 = *(const bf16x8*)(pa + 2560);                                  \
    bf16x8 a6 = *(const bf16x8*)(pa + 3072);                                  \
    bf16x8 a7 = *(const bf16x8*)(pa + 3584);                                  \
    gload16(Bsrc0 + ks_, &sB[bs_][d0]);                                       \
    gload16(Bsrc1 + ks_, &sB[bs_][d1]);                                       \
    __builtin_amdgcn_s_setprio(1);                                            \
    MF(a4, b0, 4, 0); MF(a4, b1, 4, 1); MF(a4, b2, 4, 2); MF(a4, b3, 4, 3);   \
    MF(a5, b0, 5, 0); MF(a5, b1, 5, 1); MF(a5, b2, 5, 2); MF(a5, b3, 5, 3);   \
    MF(a6, b0, 6, 0); MF(a6, b1, 6, 1); MF(a6, b2, 6, 2); MF(a6, b3, 6, 3);   \
    MF(a7, b0, 7, 0); MF(a7, b1, 7, 1); MF(a7, b2, 7, 2); MF(a7, b3, 7, 3);   \
    __builtin_amdgcn_s_setprio(0);                                            \
  }

__global__ __launch_bounds__(512, 2) void matry_gemm(
    const ushort* __restrict__ xbf,   // [16384][4096] bf16
    const ushort* __restrict__ w0,    // [1024][1024]
    const ushort* __restrict__ w1,    // [1024][2048]
    const ushort* __restrict__ w2,    // [2048][4096]
    float* __restrict__ out) {        // [16384][4096] f32
  __shared__ __align__(16) ushort sA[4][TILE_E];
  __shared__ __align__(16) ushort sB[4][TILE_E];

  const int bid = blockIdx.x;
  const int rt = bid & 63;    // row tile fastest: same-rt blocks (A reuse)
  const int ct = bid >> 6;    // land on the same XCD (64 % 8 == 0)

  int K; const ushort* W; int nl0;
  if (ct < 4)      { K = 1024; W = w0; nl0 = ct * 256; }
  else if (ct < 8) { K = 2048; W = w1; nl0 = (ct - 4) * 256; }
  else             { K = 4096; W = w2; nl0 = (ct - 8) * 256; }
  const int NT = K >> 5;          // K-tiles of 32 (32/64/128 — always even)
  const int m0 = rt * 256;
  const int n0 = ct * 256;

  const int tid  = threadIdx.x;
  const int wid  = tid >> 6;
  const int lane = tid & 63;
  const int wm = wid >> 2;        // 0..1  (row half)
  const int wn = wid & 3;         // 0..3  (col quarter)
  const int fr = lane & 15;
  // conflict-free slot (round 3, verified 0 conflicts):
  // quad = 4*(fr&1) + (h ^ ((fr>>1)&3)) covers all 8 bank-quads per 8 lanes
  const int swz_e = (((lane >> 4) ^ ((lane >> 1) & 3)) << 3);

  // ---- staging (pre-swizzled global source, linear LDS dest) ----
  // LDS slot s of row r holds k-chunk  s ^ ((r>>1)&3).
  const int srow = tid >> 2;                                   // 0..127
  const int scol = (((tid & 3) ^ ((tid >> 3) & 3)) << 3);      // elements
  const ushort* Asrc0 = xbf + (size_t)(m0 + srow) * 4096 + scol;
  const ushort* Asrc1 = Asrc0 + (size_t)128 * 4096;
  const ushort* Bsrc0 = W + (size_t)(nl0 + srow) * K + scol;
  const ushort* Bsrc1 = Bsrc0 + (size_t)128 * K;
  const int d0 = tid * 8;          // LDS element offset, issue 0
  const int d1 = 4096 + tid * 8;   // issue 1 (rows 128..255)

  f32x4 acc[8][4];
#pragma unroll
  for (int mi = 0; mi < 8; ++mi)
#pragma unroll
    for (int ni = 0; ni < 4; ++ni)
      acc[mi][ni] = (f32x4){0.f, 0.f, 0.f, 0.f};

  // ---- prologue: stage tiles 0,1 into bufs 0,1 ----
#pragma unroll
  for (int pt = 0; pt < 2; ++pt) {
    const int ks = pt * 32;
    gload16(Asrc0 + ks, &sA[pt][d0]);
    gload16(Asrc1 + ks, &sA[pt][d1]);
    gload16(Bsrc0 + ks, &sB[pt][d0]);
    gload16(Bsrc1 + ks, &sB[pt][d1]);
  }
  asm volatile("s_waitcnt vmcnt(4)" ::: "memory");  // tile 0 landed
  __builtin_amdgcn_s_barrier();

  // ---- main loop: superstep of 2 K-tiles, ONE barrier per superstep ----
  for (int t = 0; t < NT; t += 2) {
    TILE_BODY(t);
    // wave-local: drains tile t+1's stage (4 oldest of 8) before body 2
    asm volatile("s_waitcnt vmcnt(4)" ::: "memory");
    TILE_BODY(t + 1);
    // drains tile t+2's stage (read at next superstep start)
    asm volatile("s_waitcnt vmcnt(4)" ::: "memory");
    __builtin_amdgcn_s_barrier();
  }

  // ---- epilogue: C/D layout col=lane&15, row=(lane>>4)*4+reg [m89] ----
  const int rq = (lane >> 4) * 4;
#pragma unroll
  for (int mi = 0; mi < 8; ++mi) {
#pragma unroll
    for (int ni = 0; ni < 4; ++ni) {
      const int n = n0 + wn * 64 + ni * 16 + fr;
#pragma unroll
      for (int r = 0; r < 4; ++r) {
        const int m = m0 + wm * 128 + mi * 16 + rq + r;
        out[(size_t)m * 4096 + n] = acc[mi][ni][r];
      }
    }
  }
}

// Correct-but-slow fallback if workspace is too small.
__global__ void naive_kernel(const float* __restrict__ x,
                             const float* __restrict__ W0,
                             const float* __restrict__ W1,
                             const float* __restrict__ W2,
                             float* __restrict__ out) {
  long idx = (long)blockIdx.x * 256 + threadIdx.x;
  int n = (int)(idx & 4095);
  long m = idx >> 12;
  int K; const float* W; int nl;
  if (n < 1024)      { K = 1024; W = W0; nl = n; }
  else if (n < 2048) { K = 2048; W = W1; nl = n - 1024; }
  else               { K = 4096; W = W2; nl = n - 2048; }
  const float* xr = x + m * 4096;
  const float* wr = W + (long)nl * K;
  float s = 0.f;
  for (int k = 0; k < K; ++k) s += xr[k] * wr[k];
  out[idx] = s;
}

extern "C" void kernel_launch(void* const* d_in, const int* in_sizes, int n_in,
                              void* d_out, int out_size, void* d_ws,
                              size_t ws_size, hipStream_t stream) {
  const float* x  = (const float*)d_in[0];
  const float* W0 = (const float*)d_in[1];
  const float* W1 = (const float*)d_in[2];
  const float* W2 = (const float*)d_in[3];
  float* out = (float*)d_out;

  const size_t xN  = (size_t)16384 * 4096;
  const size_t w0N = (size_t)1024 * 1024;
  const size_t w1N = (size_t)1024 * 2048;
  const size_t w2N = (size_t)2048 * 4096;
  const size_t need = (xN + w0N + w1N + w2N) * sizeof(ushort);  // ~150 MB

  if (ws_size >= need) {
    ushort* xbf = (ushort*)d_ws;
    ushort* w0b = xbf + xN;
    ushort* w1b = w0b + w0N;
    ushort* w2b = w1b + w1N;
    cvt_all_bf16<<<4096, 256, 0, stream>>>(x, W0, W1, W2, xbf);
    // grid: 64 row-tiles (fast) x 16 col-tiles (slow)
    matry_gemm<<<1024, 512, 0, stream>>>(xbf, w0b, w1b, w2b, out);
  } else {
    naive_kernel<<<(int)((xN + 255) / 256), 256, 0, stream>>>(x, W0, W1, W2, out);
  }
}

// Round 11
// 450.689 us; speedup vs baseline: 5.6414x; 1.0994x over previous
//
#include <hip/hip_runtime.h>
#include <hip/hip_bf16.h>

// Matryoshka linear: y[m][n] = sum_k x[m][k] * W_seg[n_local][k]
//   seg0: n in [0,1024),    K=1024, W0 [1024][1024]
//   seg1: n in [1024,2048), K=2048, W1 [1024][2048]
//   seg2: n in [2048,4096), K=4096, W2 [2048][4096]
// M = 16384, out [16384][4096] fp32.
//
// Round 11 = round 3 verbatim (the measured optimum: 452 us total, GEMM
// 398 us / ~950 TF, MfmaUtil 46%, 0 bank conflicts). Rounds 4-10 explored
// phase-bracketing, B-in-registers, BK=64 multi-phase, 2 blocks/CU,
// 32x32x16, and superstep sync around this structure — all regressed.
// Locking the empirical best back in.
//
// Structure: bf16 convert into ws (x bf16 = 134 MB -> L3-resident), then
// one fused MFMA GEMM: 256x256 tile, BK=32, 8 waves (2x4), 4-buffer LDS
// rotation, prefetch distance 3, counted vmcnt(8) (never 0 in loop), ONE
// barrier per K-tile, conflict-free XOR swizzle:
//   reader slot = h ^ ((fr>>1)&3)  (quad = 4*(fr&1) + slot covers all 8
//   bank-quads per consecutive 8-lane group; verified 0 conflicts)
//   stager: LDS slot s of row r holds k-chunk s ^ ((r>>1)&3).

typedef short bf16x8 __attribute__((ext_vector_type(8)));
typedef float f32x4 __attribute__((ext_vector_type(4)));

__device__ __forceinline__ ushort f2bf(float f) {
  union { float f; unsigned u; } c; c.f = f;
  unsigned u = c.u;
  unsigned r = u + 0x7fffu + ((u >> 16) & 1u);  // RNE
  return (ushort)(r >> 16);
}

// One fused convert: dst (bf16) is contiguous in ws = [x | W0 | W1 | W2].
__global__ void cvt_all_bf16(const float* __restrict__ x,
                             const float* __restrict__ W0,
                             const float* __restrict__ W1,
                             const float* __restrict__ W2,
                             ushort* __restrict__ dst) {
  const int X4  = 16777216;             // xN/4
  const int E0  = X4 + 262144;          // + w0N/4
  const int E1  = E0 + 524288;          // + w1N/4
  const int E2  = E1 + 2097152;         // + w2N/4 (total float4 count)
  int i = blockIdx.x * blockDim.x + threadIdx.x;
  int stride = gridDim.x * blockDim.x;
  ushort4* out4 = (ushort4*)dst;
  for (int j = i; j < E2; j += stride) {
    const float4* src;
    if (j < X4)      src = (const float4*)x  + j;
    else if (j < E0) src = (const float4*)W0 + (j - X4);
    else if (j < E1) src = (const float4*)W1 + (j - E0);
    else             src = (const float4*)W2 + (j - E1);
    float4 v = *src;
    ushort4 o;
    o.x = f2bf(v.x); o.y = f2bf(v.y); o.z = f2bf(v.z); o.w = f2bf(v.w);
    out4[j] = o;
  }
}

__device__ __forceinline__ void gload16(const ushort* g, const ushort* l) {
  __builtin_amdgcn_global_load_lds(
      (const __attribute__((address_space(1))) void*)g,
      (__attribute__((address_space(3))) void*)l, 16, 0, 0);
}

#define TILE_E 8192   // one 256x32 bf16 tile = 16 KB = 8192 ushorts

#define MF(av, bv, mi, ni) \
  acc[mi][ni] = __builtin_amdgcn_mfma_f32_16x16x32_bf16(av, bv, acc[mi][ni], 0, 0, 0)

__global__ __launch_bounds__(512, 2) void matry_gemm(
    const ushort* __restrict__ xbf,   // [16384][4096] bf16
    const ushort* __restrict__ w0,    // [1024][1024]
    const ushort* __restrict__ w1,    // [1024][2048]
    const ushort* __restrict__ w2,    // [2048][4096]
    float* __restrict__ out) {        // [16384][4096] f32
  __shared__ __align__(16) ushort sA[4][TILE_E];
  __shared__ __align__(16) ushort sB[4][TILE_E];

  const int bid = blockIdx.x;
  const int rt = bid & 63;    // row tile fastest: same-rt blocks (A reuse)
  const int ct = bid >> 6;    // land on the same XCD (64 % 8 == 0)

  int K; const ushort* W; int nl0;
  if (ct < 4)      { K = 1024; W = w0; nl0 = ct * 256; }
  else if (ct < 8) { K = 2048; W = w1; nl0 = (ct - 4) * 256; }
  else             { K = 4096; W = w2; nl0 = (ct - 8) * 256; }
  const int NT = K >> 5;          // K-tiles of 32 (>=32)
  const int m0 = rt * 256;
  const int n0 = ct * 256;

  const int tid  = threadIdx.x;
  const int wid  = tid >> 6;
  const int lane = tid & 63;
  const int wm = wid >> 2;        // 0..1  (row half)
  const int wn = wid & 3;         // 0..3  (col quarter)
  const int fr = lane & 15;
  // conflict-free slot (verified 0 conflicts):
  // quad = 4*(fr&1) + (h ^ ((fr>>1)&3)) covers all 8 bank-quads per 8 lanes
  const int swz_e = (((lane >> 4) ^ ((lane >> 1) & 3)) << 3);

  // ---- staging (pre-swizzled global source, linear LDS dest) ----
  // LDS slot s of row r holds k-chunk  s ^ ((r>>1)&3).
  const int srow = tid >> 2;                                   // 0..127
  const int scol = (((tid & 3) ^ ((tid >> 3) & 3)) << 3);      // elements
  const ushort* Asrc0 = xbf + (size_t)(m0 + srow) * 4096 + scol;
  const ushort* Asrc1 = Asrc0 + (size_t)128 * 4096;
  const ushort* Bsrc0 = W + (size_t)(nl0 + srow) * K + scol;
  const ushort* Bsrc1 = Bsrc0 + (size_t)128 * K;
  const int d0 = tid * 8;          // LDS element offset, issue 0
  const int d1 = 4096 + tid * 8;   // issue 1 (rows 128..255)

  f32x4 acc[8][4];
#pragma unroll
  for (int mi = 0; mi < 8; ++mi)
#pragma unroll
    for (int ni = 0; ni < 4; ++ni)
      acc[mi][ni] = (f32x4){0.f, 0.f, 0.f, 0.f};

  // ---- prologue: stage tiles 0,1,2 into bufs 0,1,2 ----
#pragma unroll
  for (int pt = 0; pt < 3; ++pt) {
    const int ks = pt * 32;
    gload16(Asrc0 + ks, &sA[pt][d0]);
    gload16(Asrc1 + ks, &sA[pt][d1]);
    gload16(Bsrc0 + ks, &sB[pt][d0]);
    gload16(Bsrc1 + ks, &sB[pt][d1]);
  }
  asm volatile("s_waitcnt vmcnt(8)" ::: "memory");  // tile 0 landed
  __builtin_amdgcn_s_barrier();

  // ---- main loop: 1 K-tile per iteration, 2 MFMA phases ----
  for (int t = 0; t < NT; ++t) {
    const int b = t & 3;
    const ushort* pa = &sA[b][(wm * 128 + fr) * 32 + swz_e];
    const ushort* pb = &sB[b][(wn * 64 + fr) * 32 + swz_e];
    // stage tile t+3 (clamped in the tail: redundant but keeps vmcnt math)
    const int ts = (t + 3 < NT) ? (t + 3) : (NT - 1);
    const int ks = ts << 5;
    const int bs = (t + 3) & 3;

    // ---- phase A: quadrant mi 0..3 ----
    bf16x8 a0 = *(const bf16x8*)(pa);
    bf16x8 a1 = *(const bf16x8*)(pa + 512);
    bf16x8 a2 = *(const bf16x8*)(pa + 1024);
    bf16x8 a3 = *(const bf16x8*)(pa + 1536);
    bf16x8 b0 = *(const bf16x8*)(pb);
    bf16x8 b1 = *(const bf16x8*)(pb + 512);
    bf16x8 b2 = *(const bf16x8*)(pb + 1024);
    bf16x8 b3 = *(const bf16x8*)(pb + 1536);
    gload16(Asrc0 + ks, &sA[bs][d0]);
    gload16(Asrc1 + ks, &sA[bs][d1]);
    __builtin_amdgcn_s_setprio(1);
    MF(a0, b0, 0, 0); MF(a0, b1, 0, 1); MF(a0, b2, 0, 2); MF(a0, b3, 0, 3);
    MF(a1, b0, 1, 0); MF(a1, b1, 1, 1); MF(a1, b2, 1, 2); MF(a1, b3, 1, 3);
    MF(a2, b0, 2, 0); MF(a2, b1, 2, 1); MF(a2, b2, 2, 2); MF(a2, b3, 2, 3);
    MF(a3, b0, 3, 0); MF(a3, b1, 3, 1); MF(a3, b2, 3, 2); MF(a3, b3, 3, 3);
    __builtin_amdgcn_s_setprio(0);

    // ---- phase B: quadrant mi 4..7 ----
    bf16x8 a4 = *(const bf16x8*)(pa + 2048);
    bf16x8 a5 = *(const bf16x8*)(pa + 2560);
    bf16x8 a6 = *(const bf16x8*)(pa + 3072);
    bf16x8 a7 = *(const bf16x8*)(pa + 3584);
    gload16(Bsrc0 + ks, &sB[bs][d0]);
    gload16(Bsrc1 + ks, &sB[bs][d1]);
    __builtin_amdgcn_s_setprio(1);
    MF(a4, b0, 4, 0); MF(a4, b1, 4, 1); MF(a4, b2, 4, 2); MF(a4, b3, 4, 3);
    MF(a5, b0, 5, 0); MF(a5, b1, 5, 1); MF(a5, b2, 5, 2); MF(a5, b3, 5, 3);
    MF(a6, b0, 6, 0); MF(a6, b1, 6, 1); MF(a6, b2, 6, 2); MF(a6, b3, 6, 3);
    MF(a7, b0, 7, 0); MF(a7, b1, 7, 1); MF(a7, b2, 7, 2); MF(a7, b3, 7, 3);
    __builtin_amdgcn_s_setprio(0);

    // tile t+1's 4 loads (issued at iter t-2) are the oldest of 12 in flight
    asm volatile("s_waitcnt vmcnt(8)" ::: "memory");
    __builtin_amdgcn_s_barrier();
  }

  // ---- epilogue: C/D layout col=lane&15, row=(lane>>4)*4+reg [m89] ----
  const int rq = (lane >> 4) * 4;
#pragma unroll
  for (int mi = 0; mi < 8; ++mi) {
#pragma unroll
    for (int ni = 0; ni < 4; ++ni) {
      const int n = n0 + wn * 64 + ni * 16 + fr;
#pragma unroll
      for (int r = 0; r < 4; ++r) {
        const int m = m0 + wm * 128 + mi * 16 + rq + r;
        out[(size_t)m * 4096 + n] = acc[mi][ni][r];
      }
    }
  }
}

// Correct-but-slow fallback if workspace is too small for bf16 copies.
__global__ void naive_kernel(const float* __restrict__ x,
                             const float* __restrict__ W0,
                             const float* __restrict__ W1,
                             const float* __restrict__ W2,
                             float* __restrict__ out) {
  long idx = (long)blockIdx.x * 256 + threadIdx.x;
  int n = (int)(idx & 4095);
  long m = idx >> 12;
  int K; const float* W; int nl;
  if (n < 1024)      { K = 1024; W = W0; nl = n; }
  else if (n < 2048) { K = 2048; W = W1; nl = n - 1024; }
  else               { K = 4096; W = W2; nl = n - 2048; }
  const float* xr = x + m * 4096;
  const float* wr = W + (long)nl * K;
  float s = 0.f;
  for (int k = 0; k < K; ++k) s += xr[k] * wr[k];
  out[idx] = s;
}

extern "C" void kernel_launch(void* const* d_in, const int* in_sizes, int n_in,
                              void* d_out, int out_size, void* d_ws,
                              size_t ws_size, hipStream_t stream) {
  const float* x  = (const float*)d_in[0];
  const float* W0 = (const float*)d_in[1];
  const float* W1 = (const float*)d_in[2];
  const float* W2 = (const float*)d_in[3];
  float* out = (float*)d_out;

  const size_t xN  = (size_t)16384 * 4096;
  const size_t w0N = (size_t)1024 * 1024;
  const size_t w1N = (size_t)1024 * 2048;
  const size_t w2N = (size_t)2048 * 4096;
  const size_t need = (xN + w0N + w1N + w2N) * sizeof(ushort);  // ~150 MB

  if (ws_size >= need) {
    ushort* xbf = (ushort*)d_ws;
    ushort* w0b = xbf + xN;
    ushort* w1b = w0b + w0N;
    ushort* w2b = w1b + w1N;
    cvt_all_bf16<<<4096, 256, 0, stream>>>(x, W0, W1, W2, xbf);
    // grid: 64 row-tiles (fast) x 16 col-tiles (slow)
    matry_gemm<<<1024, 512, 0, stream>>>(xbf, w0b, w1b, w2b, out);
  } else {
    naive_kernel<<<(int)((xN + 255) / 256), 256, 0, stream>>>(x, W0, W1, W2, out);
  }
}